// Round 7
// baseline (1242.281 us; speedup 1.0000x reference)
//
#include <hip/hip_runtime.h>
#include <hip/hip_fp16.h>

#define NF 21
#define HSTR 32     // fp16 row stride (halves): 64B rows -> 1 cache line per row
#define BN 12       // nodes per block in gather kernels (12*21 = 252 lanes used)
#define SCAN_T 1024

#define ATOMIC_ADD_F32(p, v) unsafeAtomicAdd((p), (v))

// Diagnostic: fills output with a recognizable sentinel if ws_size is insufficient.
__global__ __launch_bounds__(64) void sentinel_kernel(float* out, int m) {
    int i = blockIdx.x * 64 + threadIdx.x;
    if (i < m) out[i] = 0.109375f;
}

// --- CSR build ---------------------------------------------------------------

__global__ __launch_bounds__(256) void hist_kernel(
    const int* __restrict__ ei, int* __restrict__ counts, int E) {
    int e = blockIdx.x * 256 + threadIdx.x;
    if (e >= E) return;
    atomicAdd(&counts[ei[E + e]], 1);
}

// single-block exclusive scan in-place over data[0..n)
__global__ __launch_bounds__(SCAN_T) void scan_kernel(int* __restrict__ data, int n) {
    __shared__ int sd[SCAN_T];
    int t = threadIdx.x;
    int chunk = (n + SCAN_T - 1) / SCAN_T;
    int base = t * chunk;
    int s = 0;
    for (int i = 0; i < chunk; ++i) { int idx = base + i; if (idx < n) s += data[idx]; }
    sd[t] = s;
    __syncthreads();
    for (int off = 1; off < SCAN_T; off <<= 1) {
        int v = (t >= off) ? sd[t - off] : 0;
        __syncthreads();
        sd[t] += v;
        __syncthreads();
    }
    int run = sd[t] - s;
    for (int i = 0; i < chunk; ++i) {
        int idx = base + i;
        if (idx < n) { int v = data[idx]; data[idx] = run; run += v; }
    }
}

// scatter edges into CSR; rowptr[d] bumps from start(d) to end(d).
// After: segment(d) = [ d==0 ? 0 : rowptr[d-1], rowptr[d] ).
__global__ __launch_bounds__(256) void scatter_kernel(
    const int* __restrict__ ei, const float* __restrict__ ew,
    int* __restrict__ rowptr, int2* __restrict__ csr, int E) {
    int e = blockIdx.x * 256 + threadIdx.x;
    if (e >= E) return;
    int s = ei[e], d = ei[E + e];
    int pos = atomicAdd(&rowptr[d], 1);
    csr[pos] = make_int2(s, __float_as_int(ew[e]));
}

static __device__ __forceinline__ void csr_nt(const int2* csr, int e, int& s, float& w) {
    long long cl = __builtin_nontemporal_load((const long long*)csr + e);
    s = (int)(cl & 0xffffffffLL);
    w = __int_as_float((int)(cl >> 32));
}

// --- Layer 1: deg from CSR, dinv, y = dinv*(x@W1) (fp16 out) ----------------
__global__ __launch_bounds__(256) void node_l1_kernel(
    const float* __restrict__ x, const int* __restrict__ rowptr,
    const int2* __restrict__ csr, const float* __restrict__ W,
    float* __restrict__ dinv, __half* __restrict__ y, int n) {
    __shared__ float Ws[NF * NF];
    for (int i = threadIdx.x; i < NF * NF; i += 256) Ws[i] = W[i];
    __syncthreads();
    int i = blockIdx.x * 256 + threadIdx.x;
    if (i >= n) return;
    int start = (i == 0) ? 0 : rowptr[i - 1], end = rowptr[i];
    float deg = 0.f;
    for (int e = start; e < end; ++e) {
        int s; float w; csr_nt(csr, e, s, w);
        deg += w;
    }
    float di = rsqrtf(deg + 1.0f);
    dinv[i] = di;
    float xr[NF];
    #pragma unroll
    for (int f = 0; f < NF; ++f) xr[f] = x[i * NF + f];
    #pragma unroll
    for (int j = 0; j < NF; ++j) {
        float v = 0.f;
        #pragma unroll
        for (int f = 0; f < NF; ++f) v += xr[f] * Ws[f * NF + j];
        y[(size_t)i * HSTR + j] = __float2half(di * v);
    }
}

// --- Fused GCN layer (layers 2,3): gather + prev finish + matvec ------------
__global__ __launch_bounds__(256) void layer_kernel(
    const int* __restrict__ rowptr, const int2* __restrict__ csr,
    const float* __restrict__ dinv, const float* __restrict__ bprev,
    const float* __restrict__ W,
    const __half* __restrict__ yin, __half* __restrict__ yout, int n) {
    __shared__ float Ws[NF * NF];
    __shared__ float bsh[NF];
    __shared__ float xr[BN][NF];
    for (int i = threadIdx.x; i < NF * NF; i += 256) Ws[i] = W[i];
    if (threadIdx.x < NF) bsh[threadIdx.x] = bprev[threadIdx.x];
    __syncthreads();
    int t = threadIdx.x;
    int nd = t / NF, f = t - nd * NF;
    int d = blockIdx.x * BN + nd;
    bool act = (nd < BN) && (d < n);
    float di = 0.f;
    if (act) {
        di = dinv[d];
        float g = 0.f;
        int start = (d == 0) ? 0 : rowptr[d - 1], end = rowptr[d];
        for (int e = start; e < end; ++e) {
            int s; float w; csr_nt(csr, e, s, w);
            g += w * __half2float(yin[(size_t)s * HSTR + f]);  // one 64B line per row
        }
        xr[nd][f] = di * (g + __half2float(yin[(size_t)d * HSTR + f])) + bsh[f];
    }
    __syncthreads();
    if (act) {
        float v = 0.f;
        #pragma unroll
        for (int k = 0; k < NF; ++k) v += xr[nd][k] * Ws[k * NF + f];
        yout[(size_t)d * HSTR + f] = __float2half(di * v);
    }
}

// --- Final fused: gather + relu + block-level mean-pool partials ------------
__global__ __launch_bounds__(256) void final_pool_kernel(
    const int* __restrict__ rowptr, const int2* __restrict__ csr,
    const float* __restrict__ dinv, const float* __restrict__ b3,
    const int* __restrict__ batch, const __half* __restrict__ yin,
    float* __restrict__ sums, float* __restrict__ cnt, int n) {
    __shared__ float bsh[NF];
    __shared__ float xr[BN][NF];
    __shared__ int gs[BN];
    if (threadIdx.x < NF) bsh[threadIdx.x] = b3[threadIdx.x];
    __syncthreads();
    int t = threadIdx.x;
    int nd = t / NF, f = t - nd * NF;
    int base = blockIdx.x * BN;
    int nvalid = n - base; if (nvalid > BN) nvalid = BN;
    int d = base + nd;
    bool act = (nd < BN) && (d < n);
    if (act) {
        float g = 0.f;
        int start = (d == 0) ? 0 : rowptr[d - 1], end = rowptr[d];
        for (int e = start; e < end; ++e) {
            int s; float w; csr_nt(csr, e, s, w);
            g += w * __half2float(yin[(size_t)s * HSTR + f]);
        }
        float h = dinv[d] * (g + __half2float(yin[(size_t)d * HSTR + f])) + bsh[f];
        xr[nd][f] = fmaxf(h, 0.f);
        if (f == 0) gs[nd] = batch[d];
    }
    __syncthreads();
    if (nvalid <= 0) return;
    if (t < NF) {           // per-feature: run-length pooled atomics (batch sorted)
        float run = 0.f;
        int gcur = gs[0];
        for (int k = 0; k < nvalid; ++k) {
            int g = gs[k];
            if (g != gcur) { ATOMIC_ADD_F32(&sums[gcur * NF + t], run); run = 0.f; gcur = g; }
            run += xr[k][t];
        }
        ATOMIC_ADD_F32(&sums[gcur * NF + t], run);
    } else if (t == NF) {   // node counts per graph
        float run = 0.f;
        int gcur = gs[0];
        for (int k = 0; k < nvalid; ++k) {
            int g = gs[k];
            if (g != gcur) { ATOMIC_ADD_F32(&cnt[gcur], run); run = 0.f; gcur = g; }
            run += 1.f;
        }
        ATOMIC_ADD_F32(&cnt[gcur], run);
    }
}

// --- MLP + softmax: one block per graph; fp32 output -------------------------
__global__ __launch_bounds__(256) void mlp_kernel(
    const float* __restrict__ sums, const float* __restrict__ cnt,
    const float* __restrict__ Wp,  const float* __restrict__ bp,
    const float* __restrict__ Wf1, const float* __restrict__ bf1,
    const float* __restrict__ Wf2, const float* __restrict__ bf2,
    const float* __restrict__ Wo,  const float* __restrict__ bo,
    float* __restrict__ out) {
    int g = blockIdx.x;
    int t = threadIdx.x;
    __shared__ float xr[NF], h1[128], h2[256], h3[64];
    if (t < NF) xr[t] = sums[g * NF + t] / fmaxf(cnt[g], 1.0f);
    __syncthreads();
    if (t < 128) {
        float v = bp[t];
        #pragma unroll
        for (int f = 0; f < NF; ++f) v += xr[f] * Wp[f * 128 + t];
        h1[t] = v >= 0.f ? v : 0.01f * v;
    }
    __syncthreads();
    {
        float v = bf1[t];
        for (int k = 0; k < 128; ++k) v += h1[k] * Wf1[k * 256 + t];
        h2[t] = v >= 0.f ? v : 0.01f * v;
    }
    __syncthreads();
    if (t < 64) {
        float v = bf2[t];
        for (int k = 0; k < 256; ++k) v += h2[k] * Wf2[k * 64 + t];
        h3[t] = v >= 0.f ? v : 0.01f * v;
    }
    __syncthreads();
    if (t == 0) {
        float lg[5];
        float m = -1e30f;
        for (int j = 0; j < 5; ++j) {
            float v = bo[j];
            for (int k = 0; k < 64; ++k) v += h3[k] * Wo[k * 5 + j];
            lg[j] = v;
            m = fmaxf(m, v);
        }
        float den = 0.f;
        for (int j = 0; j < 5; ++j) { lg[j] = __expf(lg[j] - m); den += lg[j]; }
        for (int j = 0; j < 5; ++j) out[g * 5 + j] = lg[j] / den;
    }
}

extern "C" void kernel_launch(void* const* d_in, const int* in_sizes, int n_in,
                              void* d_out, int out_size, void* d_ws, size_t ws_size,
                              hipStream_t stream) {
    const float* x     = (const float*)d_in[0];
    const int*   ei    = (const int*)d_in[1];
    const float* ew    = (const float*)d_in[2];
    const int*   batch = (const int*)d_in[3];
    const float* W1 = (const float*)d_in[4];
    const float* b1 = (const float*)d_in[5];
    const float* W2 = (const float*)d_in[6];
    const float* b2 = (const float*)d_in[7];
    const float* W3 = (const float*)d_in[8];
    const float* b3 = (const float*)d_in[9];
    const float* Wp  = (const float*)d_in[10];
    const float* bp  = (const float*)d_in[11];
    const float* Wf1 = (const float*)d_in[12];
    const float* bf1 = (const float*)d_in[13];
    const float* Wf2 = (const float*)d_in[14];
    const float* bf2 = (const float*)d_in[15];
    const float* Wo  = (const float*)d_in[16];
    const float* bo  = (const float*)d_in[17];

    const int n = in_sizes[0] / NF;   // 100000
    const int E = in_sizes[2];        // 3200000
    const int B = out_size / 5;       // 64

    // ws layout (4B words): csr int2[E] | rowptr[n] | dinv[n] | yA half[n*HSTR/2 words] | yB | sums[B*NF] | cnt[B]
    const size_t y_words = ((size_t)n * HSTR) / 2;
    const size_t need_words = (size_t)2 * E + 2 * (size_t)n + 2 * y_words + (size_t)B * NF + B;
    if (ws_size < need_words * 4) {
        sentinel_kernel<<<(out_size + 63) / 64, 64, 0, stream>>>((float*)d_out, out_size);
        return;
    }

    int2*  csr    = (int2*)d_ws;
    int*   rowptr = (int*)d_ws + (size_t)2 * E;
    float* dinv   = (float*)((int*)d_ws + (size_t)2 * E + n);
    __half* yA    = (__half*)(dinv + n);
    __half* yB    = yA + (size_t)n * HSTR;
    float* sums   = (float*)(yB + (size_t)n * HSTR);
    float* cnt    = sums + (size_t)B * NF;

    hipMemsetAsync(rowptr, 0, (size_t)n * sizeof(int), stream);
    hipMemsetAsync(sums, 0, (size_t)(B * NF + B) * sizeof(float), stream);

    int nb_e = (E + 255) / 256;
    int nb_n = (n + 255) / 256;
    int nb_g = (n + BN - 1) / BN;

    hist_kernel<<<nb_e, 256, 0, stream>>>(ei, rowptr, E);
    scan_kernel<<<1, SCAN_T, 0, stream>>>(rowptr, n);
    scatter_kernel<<<nb_e, 256, 0, stream>>>(ei, ew, rowptr, csr, E);

    node_l1_kernel<<<nb_n, 256, 0, stream>>>(x, rowptr, csr, W1, dinv, yA, n);
    layer_kernel<<<nb_g, 256, 0, stream>>>(rowptr, csr, dinv, b1, W2, yA, yB, n);
    layer_kernel<<<nb_g, 256, 0, stream>>>(rowptr, csr, dinv, b2, W3, yB, yA, n);
    final_pool_kernel<<<nb_g, 256, 0, stream>>>(rowptr, csr, dinv, b3, batch, yA,
                                                sums, cnt, n);
    mlp_kernel<<<B, 256, 0, stream>>>(sums, cnt, Wp, bp, Wf1, bf1, Wf2, bf2, Wo, bo,
                                      (float*)d_out);
}

// Round 8
// 1107.997 us; speedup vs baseline: 1.1212x; 1.1212x over previous
//
#include <hip/hip_runtime.h>
#include <hip/hip_fp16.h>

#define NF 21
#define HSTR 32     // fp16 row stride (halves): 64B rows -> 1 cache line per row
#define BN 12       // nodes per block in gather kernels (12*21 = 252 lanes used)
#define SCAN_T 1024

#define ATOMIC_ADD_F32(p, v) unsafeAtomicAdd((p), (v))

// Diagnostic: fills output with a recognizable sentinel if ws_size is insufficient.
__global__ __launch_bounds__(64) void sentinel_kernel(float* out, int m) {
    int i = blockIdx.x * 64 + threadIdx.x;
    if (i < m) out[i] = 0.109375f;
}

// --- CSR build ---------------------------------------------------------------

__global__ __launch_bounds__(256) void hist_kernel(
    const int* __restrict__ ei, int* __restrict__ counts, int E) {
    int e = blockIdx.x * 256 + threadIdx.x;
    if (e >= E) return;
    atomicAdd(&counts[ei[E + e]], 1);
}

// single-block exclusive scan in-place over data[0..n)
__global__ __launch_bounds__(SCAN_T) void scan_kernel(int* __restrict__ data, int n) {
    __shared__ int sd[SCAN_T];
    int t = threadIdx.x;
    int chunk = (n + SCAN_T - 1) / SCAN_T;
    int base = t * chunk;
    int s = 0;
    for (int i = 0; i < chunk; ++i) { int idx = base + i; if (idx < n) s += data[idx]; }
    sd[t] = s;
    __syncthreads();
    for (int off = 1; off < SCAN_T; off <<= 1) {
        int v = (t >= off) ? sd[t - off] : 0;
        __syncthreads();
        sd[t] += v;
        __syncthreads();
    }
    int run = sd[t] - s;
    for (int i = 0; i < chunk; ++i) {
        int idx = base + i;
        if (idx < n) { int v = data[idx]; data[idx] = run; run += v; }
    }
}

// scatter edges into CSR; rowptr[d] bumps from start(d) to end(d).
// After: segment(d) = [ d==0 ? 0 : rowptr[d-1], rowptr[d] ).
__global__ __launch_bounds__(256) void scatter_kernel(
    const int* __restrict__ ei, const float* __restrict__ ew,
    int* __restrict__ rowptr, int2* __restrict__ csr, int E) {
    int e = blockIdx.x * 256 + threadIdx.x;
    if (e >= E) return;
    int s = ei[e], d = ei[E + e];
    int pos = atomicAdd(&rowptr[d], 1);
    csr[pos] = make_int2(s, __float_as_int(ew[e]));
}

// plain cached CSR read (NT variant regressed: killed L1 reuse — r7 post-mortem)
static __device__ __forceinline__ void csr_ld(const int2* csr, int e, int& s, float& w) {
    int2 c = csr[e];
    s = c.x;
    w = __int_as_float(c.y);
}

// --- Layer 1: deg from CSR, dinv, y = dinv*(x@W1) (fp16 out) ----------------
__global__ __launch_bounds__(256) void node_l1_kernel(
    const float* __restrict__ x, const int* __restrict__ rowptr,
    const int2* __restrict__ csr, const float* __restrict__ W,
    float* __restrict__ dinv, __half* __restrict__ y, int n) {
    __shared__ float Ws[NF * NF];
    for (int i = threadIdx.x; i < NF * NF; i += 256) Ws[i] = W[i];
    __syncthreads();
    int i = blockIdx.x * 256 + threadIdx.x;
    if (i >= n) return;
    int start = (i == 0) ? 0 : rowptr[i - 1], end = rowptr[i];
    float deg = 0.f;
    for (int e = start; e < end; ++e) {
        int s; float w; csr_ld(csr, e, s, w);
        deg += w;
    }
    float di = rsqrtf(deg + 1.0f);
    dinv[i] = di;
    float xr[NF];
    #pragma unroll
    for (int f = 0; f < NF; ++f) xr[f] = x[i * NF + f];
    #pragma unroll
    for (int j = 0; j < NF; ++j) {
        float v = 0.f;
        #pragma unroll
        for (int f = 0; f < NF; ++f) v += xr[f] * Ws[f * NF + j];
        y[(size_t)i * HSTR + j] = __float2half(di * v);
    }
}

// --- Fused GCN layer (layers 2,3): gather + prev finish + matvec ------------
__global__ __launch_bounds__(256) void layer_kernel(
    const int* __restrict__ rowptr, const int2* __restrict__ csr,
    const float* __restrict__ dinv, const float* __restrict__ bprev,
    const float* __restrict__ W,
    const __half* __restrict__ yin, __half* __restrict__ yout, int n) {
    __shared__ float Ws[NF * NF];
    __shared__ float bsh[NF];
    __shared__ float xr[BN][NF];
    for (int i = threadIdx.x; i < NF * NF; i += 256) Ws[i] = W[i];
    if (threadIdx.x < NF) bsh[threadIdx.x] = bprev[threadIdx.x];
    __syncthreads();
    int t = threadIdx.x;
    int nd = t / NF, f = t - nd * NF;
    int d = blockIdx.x * BN + nd;
    bool act = (nd < BN) && (d < n);
    float di = 0.f;
    if (act) {
        di = dinv[d];
        float g = 0.f;
        int start = (d == 0) ? 0 : rowptr[d - 1], end = rowptr[d];
        for (int e = start; e < end; ++e) {
            int s; float w; csr_ld(csr, e, s, w);
            g += w * __half2float(yin[(size_t)s * HSTR + f]);  // one 64B line per row
        }
        xr[nd][f] = di * (g + __half2float(yin[(size_t)d * HSTR + f])) + bsh[f];
    }
    __syncthreads();
    if (act) {
        float v = 0.f;
        #pragma unroll
        for (int k = 0; k < NF; ++k) v += xr[nd][k] * Ws[k * NF + f];
        yout[(size_t)d * HSTR + f] = __float2half(di * v);
    }
}

// --- Final fused: gather + relu + block-level mean-pool partials ------------
__global__ __launch_bounds__(256) void final_pool_kernel(
    const int* __restrict__ rowptr, const int2* __restrict__ csr,
    const float* __restrict__ dinv, const float* __restrict__ b3,
    const int* __restrict__ batch, const __half* __restrict__ yin,
    float* __restrict__ sums, float* __restrict__ cnt, int n) {
    __shared__ float bsh[NF];
    __shared__ float xr[BN][NF];
    __shared__ int gs[BN];
    if (threadIdx.x < NF) bsh[threadIdx.x] = b3[threadIdx.x];
    __syncthreads();
    int t = threadIdx.x;
    int nd = t / NF, f = t - nd * NF;
    int base = blockIdx.x * BN;
    int nvalid = n - base; if (nvalid > BN) nvalid = BN;
    int d = base + nd;
    bool act = (nd < BN) && (d < n);
    if (act) {
        float g = 0.f;
        int start = (d == 0) ? 0 : rowptr[d - 1], end = rowptr[d];
        for (int e = start; e < end; ++e) {
            int s; float w; csr_ld(csr, e, s, w);
            g += w * __half2float(yin[(size_t)s * HSTR + f]);
        }
        float h = dinv[d] * (g + __half2float(yin[(size_t)d * HSTR + f])) + bsh[f];
        xr[nd][f] = fmaxf(h, 0.f);
        if (f == 0) gs[nd] = batch[d];
    }
    __syncthreads();
    if (nvalid <= 0) return;
    if (t < NF) {           // per-feature: run-length pooled atomics (batch sorted)
        float run = 0.f;
        int gcur = gs[0];
        for (int k = 0; k < nvalid; ++k) {
            int g = gs[k];
            if (g != gcur) { ATOMIC_ADD_F32(&sums[gcur * NF + t], run); run = 0.f; gcur = g; }
            run += xr[k][t];
        }
        ATOMIC_ADD_F32(&sums[gcur * NF + t], run);
    } else if (t == NF) {   // node counts per graph
        float run = 0.f;
        int gcur = gs[0];
        for (int k = 0; k < nvalid; ++k) {
            int g = gs[k];
            if (g != gcur) { ATOMIC_ADD_F32(&cnt[gcur], run); run = 0.f; gcur = g; }
            run += 1.f;
        }
        ATOMIC_ADD_F32(&cnt[gcur], run);
    }
}

// --- MLP + softmax: one block per graph; fp32 output -------------------------
__global__ __launch_bounds__(256) void mlp_kernel(
    const float* __restrict__ sums, const float* __restrict__ cnt,
    const float* __restrict__ Wp,  const float* __restrict__ bp,
    const float* __restrict__ Wf1, const float* __restrict__ bf1,
    const float* __restrict__ Wf2, const float* __restrict__ bf2,
    const float* __restrict__ Wo,  const float* __restrict__ bo,
    float* __restrict__ out) {
    int g = blockIdx.x;
    int t = threadIdx.x;
    __shared__ float xr[NF], h1[128], h2[256], h3[64];
    if (t < NF) xr[t] = sums[g * NF + t] / fmaxf(cnt[g], 1.0f);
    __syncthreads();
    if (t < 128) {
        float v = bp[t];
        #pragma unroll
        for (int f = 0; f < NF; ++f) v += xr[f] * Wp[f * 128 + t];
        h1[t] = v >= 0.f ? v : 0.01f * v;
    }
    __syncthreads();
    {
        float v = bf1[t];
        for (int k = 0; k < 128; ++k) v += h1[k] * Wf1[k * 256 + t];
        h2[t] = v >= 0.f ? v : 0.01f * v;
    }
    __syncthreads();
    if (t < 64) {
        float v = bf2[t];
        for (int k = 0; k < 256; ++k) v += h2[k] * Wf2[k * 64 + t];
        h3[t] = v >= 0.f ? v : 0.01f * v;
    }
    __syncthreads();
    if (t == 0) {
        float lg[5];
        float m = -1e30f;
        for (int j = 0; j < 5; ++j) {
            float v = bo[j];
            for (int k = 0; k < 64; ++k) v += h3[k] * Wo[k * 5 + j];
            lg[j] = v;
            m = fmaxf(m, v);
        }
        float den = 0.f;
        for (int j = 0; j < 5; ++j) { lg[j] = __expf(lg[j] - m); den += lg[j]; }
        for (int j = 0; j < 5; ++j) out[g * 5 + j] = lg[j] / den;
    }
}

extern "C" void kernel_launch(void* const* d_in, const int* in_sizes, int n_in,
                              void* d_out, int out_size, void* d_ws, size_t ws_size,
                              hipStream_t stream) {
    const float* x     = (const float*)d_in[0];
    const int*   ei    = (const int*)d_in[1];
    const float* ew    = (const float*)d_in[2];
    const int*   batch = (const int*)d_in[3];
    const float* W1 = (const float*)d_in[4];
    const float* b1 = (const float*)d_in[5];
    const float* W2 = (const float*)d_in[6];
    const float* b2 = (const float*)d_in[7];
    const float* W3 = (const float*)d_in[8];
    const float* b3 = (const float*)d_in[9];
    const float* Wp  = (const float*)d_in[10];
    const float* bp  = (const float*)d_in[11];
    const float* Wf1 = (const float*)d_in[12];
    const float* bf1 = (const float*)d_in[13];
    const float* Wf2 = (const float*)d_in[14];
    const float* bf2 = (const float*)d_in[15];
    const float* Wo  = (const float*)d_in[16];
    const float* bo  = (const float*)d_in[17];

    const int n = in_sizes[0] / NF;   // 100000
    const int E = in_sizes[2];        // 3200000
    const int B = out_size / 5;       // 64

    // ws layout (4B words): csr int2[E] | rowptr[n] | dinv[n] | yA half[n*HSTR/2 words] | yB | sums[B*NF] | cnt[B]
    const size_t y_words = ((size_t)n * HSTR) / 2;
    const size_t need_words = (size_t)2 * E + 2 * (size_t)n + 2 * y_words + (size_t)B * NF + B;
    if (ws_size < need_words * 4) {
        sentinel_kernel<<<(out_size + 63) / 64, 64, 0, stream>>>((float*)d_out, out_size);
        return;
    }

    int2*  csr    = (int2*)d_ws;
    int*   rowptr = (int*)d_ws + (size_t)2 * E;
    float* dinv   = (float*)((int*)d_ws + (size_t)2 * E + n);
    __half* yA    = (__half*)(dinv + n);
    __half* yB    = yA + (size_t)n * HSTR;
    float* sums   = (float*)(yB + (size_t)n * HSTR);
    float* cnt    = sums + (size_t)B * NF;

    hipMemsetAsync(rowptr, 0, (size_t)n * sizeof(int), stream);
    hipMemsetAsync(sums, 0, (size_t)(B * NF + B) * sizeof(float), stream);

    int nb_e = (E + 255) / 256;
    int nb_n = (n + 255) / 256;
    int nb_g = (n + BN - 1) / BN;

    hist_kernel<<<nb_e, 256, 0, stream>>>(ei, rowptr, E);
    scan_kernel<<<1, SCAN_T, 0, stream>>>(rowptr, n);
    scatter_kernel<<<nb_e, 256, 0, stream>>>(ei, ew, rowptr, csr, E);

    node_l1_kernel<<<nb_n, 256, 0, stream>>>(x, rowptr, csr, W1, dinv, yA, n);
    layer_kernel<<<nb_g, 256, 0, stream>>>(rowptr, csr, dinv, b1, W2, yA, yB, n);
    layer_kernel<<<nb_g, 256, 0, stream>>>(rowptr, csr, dinv, b2, W3, yB, yA, n);
    final_pool_kernel<<<nb_g, 256, 0, stream>>>(rowptr, csr, dinv, b3, batch, yA,
                                                sums, cnt, n);
    mlp_kernel<<<B, 256, 0, stream>>>(sums, cnt, Wp, bp, Wf1, bf1, Wf2, bf2, Wo, bo,
                                      (float*)d_out);
}

// Round 9
// 924.916 us; speedup vs baseline: 1.3431x; 1.1979x over previous
//
#include <hip/hip_runtime.h>
#include <hip/hip_fp16.h>

#define NF 21
#define HSTR 32     // fp16 row stride (halves): 64B rows -> 1 cache line per row
#define BN 12       // nodes per block in gather kernels (12*21 = 252 lanes used)
#define SCAN_T 1024

#define ATOMIC_ADD_F32(p, v) unsafeAtomicAdd((p), (v))

// Diagnostic: fills output with a recognizable sentinel if ws_size is insufficient.
__global__ __launch_bounds__(64) void sentinel_kernel(float* out, int m) {
    int i = blockIdx.x * 64 + threadIdx.x;
    if (i < m) out[i] = 0.109375f;
}

// --- CSR build ---------------------------------------------------------------

__global__ __launch_bounds__(256) void hist_kernel(
    const int* __restrict__ ei, int* __restrict__ counts, int E) {
    int e = blockIdx.x * 256 + threadIdx.x;
    if (e >= E) return;
    atomicAdd(&counts[ei[E + e]], 1);
}

// single-block exclusive scan in-place over data[0..n)
__global__ __launch_bounds__(SCAN_T) void scan_kernel(int* __restrict__ data, int n) {
    __shared__ int sd[SCAN_T];
    int t = threadIdx.x;
    int chunk = (n + SCAN_T - 1) / SCAN_T;
    int base = t * chunk;
    int s = 0;
    for (int i = 0; i < chunk; ++i) { int idx = base + i; if (idx < n) s += data[idx]; }
    sd[t] = s;
    __syncthreads();
    for (int off = 1; off < SCAN_T; off <<= 1) {
        int v = (t >= off) ? sd[t - off] : 0;
        __syncthreads();
        sd[t] += v;
        __syncthreads();
    }
    int run = sd[t] - s;
    for (int i = 0; i < chunk; ++i) {
        int idx = base + i;
        if (idx < n) { int v = data[idx]; data[idx] = run; run += v; }
    }
}

// scatter edges into CSR; rowptr[d] bumps from start(d) to end(d).
// After: segment(d) = [ d==0 ? 0 : rowptr[d-1], rowptr[d] ).
__global__ __launch_bounds__(256) void scatter_kernel(
    const int* __restrict__ ei, const float* __restrict__ ew,
    int* __restrict__ rowptr, int2* __restrict__ csr, int E) {
    int e = blockIdx.x * 256 + threadIdx.x;
    if (e >= E) return;
    int s = ei[e], d = ei[E + e];
    int pos = atomicAdd(&rowptr[d], 1);
    csr[pos] = make_int2(s, __float_as_int(ew[e]));
}

// --- Layer 1: deg from CSR, dinv, y = dinv*(x@W1) (fp16 out) ----------------
__global__ __launch_bounds__(256) void node_l1_kernel(
    const float* __restrict__ x, const int* __restrict__ rowptr,
    const int2* __restrict__ csr, const float* __restrict__ W,
    float* __restrict__ dinv, __half* __restrict__ y, int n) {
    __shared__ float Ws[NF * NF];
    for (int i = threadIdx.x; i < NF * NF; i += 256) Ws[i] = W[i];
    __syncthreads();
    int i = blockIdx.x * 256 + threadIdx.x;
    if (i >= n) return;
    int start = (i == 0) ? 0 : rowptr[i - 1], end = rowptr[i];
    float deg = 0.f;
    int e = start;
    for (; e + 3 < end; e += 4) {   // unrolled: 4 independent 8B reads in flight
        int2 c0 = csr[e], c1 = csr[e + 1], c2 = csr[e + 2], c3 = csr[e + 3];
        deg += __int_as_float(c0.y) + __int_as_float(c1.y)
             + __int_as_float(c2.y) + __int_as_float(c3.y);
    }
    for (; e < end; ++e) deg += __int_as_float(csr[e].y);
    float di = rsqrtf(deg + 1.0f);
    dinv[i] = di;
    float xr[NF];
    #pragma unroll
    for (int f = 0; f < NF; ++f) xr[f] = x[i * NF + f];
    #pragma unroll
    for (int j = 0; j < NF; ++j) {
        float v = 0.f;
        #pragma unroll
        for (int f = 0; f < NF; ++f) v += xr[f] * Ws[f * NF + j];
        y[(size_t)i * HSTR + j] = __float2half(di * v);
    }
}

// gather over one node's CSR segment, unrolled x8 for memory-level parallelism:
// 8 independent y-line loads in flight per lane (was 1 -> latency-chain bound).
static __device__ __forceinline__ float gather_seg(
    const int2* __restrict__ csr, const __half* __restrict__ yin,
    int start, int end, int f) {
    float g = 0.f;
    int e = start;
    for (; e + 7 < end; e += 8) {
        int2 c0 = csr[e + 0], c1 = csr[e + 1], c2 = csr[e + 2], c3 = csr[e + 3];
        int2 c4 = csr[e + 4], c5 = csr[e + 5], c6 = csr[e + 6], c7 = csr[e + 7];
        float a0 = __half2float(yin[(size_t)c0.x * HSTR + f]);
        float a1 = __half2float(yin[(size_t)c1.x * HSTR + f]);
        float a2 = __half2float(yin[(size_t)c2.x * HSTR + f]);
        float a3 = __half2float(yin[(size_t)c3.x * HSTR + f]);
        float a4 = __half2float(yin[(size_t)c4.x * HSTR + f]);
        float a5 = __half2float(yin[(size_t)c5.x * HSTR + f]);
        float a6 = __half2float(yin[(size_t)c6.x * HSTR + f]);
        float a7 = __half2float(yin[(size_t)c7.x * HSTR + f]);
        g += __int_as_float(c0.y) * a0 + __int_as_float(c1.y) * a1
           + __int_as_float(c2.y) * a2 + __int_as_float(c3.y) * a3
           + __int_as_float(c4.y) * a4 + __int_as_float(c5.y) * a5
           + __int_as_float(c6.y) * a6 + __int_as_float(c7.y) * a7;
    }
    for (; e < end; ++e) {
        int2 c = csr[e];
        g += __int_as_float(c.y) * __half2float(yin[(size_t)c.x * HSTR + f]);
    }
    return g;
}

// --- Fused GCN layer (layers 2,3): gather + prev finish + matvec ------------
__global__ __launch_bounds__(256) void layer_kernel(
    const int* __restrict__ rowptr, const int2* __restrict__ csr,
    const float* __restrict__ dinv, const float* __restrict__ bprev,
    const float* __restrict__ W,
    const __half* __restrict__ yin, __half* __restrict__ yout, int n) {
    __shared__ float Ws[NF * NF];
    __shared__ float bsh[NF];
    __shared__ float xr[BN][NF];
    for (int i = threadIdx.x; i < NF * NF; i += 256) Ws[i] = W[i];
    if (threadIdx.x < NF) bsh[threadIdx.x] = bprev[threadIdx.x];
    __syncthreads();
    int t = threadIdx.x;
    int nd = t / NF, f = t - nd * NF;
    int d = blockIdx.x * BN + nd;
    bool act = (nd < BN) && (d < n);
    float di = 0.f;
    if (act) {
        di = dinv[d];
        int start = (d == 0) ? 0 : rowptr[d - 1], end = rowptr[d];
        float g = gather_seg(csr, yin, start, end, f);
        xr[nd][f] = di * (g + __half2float(yin[(size_t)d * HSTR + f])) + bsh[f];
    }
    __syncthreads();
    if (act) {
        float v = 0.f;
        #pragma unroll
        for (int k = 0; k < NF; ++k) v += xr[nd][k] * Ws[k * NF + f];
        yout[(size_t)d * HSTR + f] = __float2half(di * v);
    }
}

// --- Final fused: gather + relu + block-level mean-pool partials ------------
__global__ __launch_bounds__(256) void final_pool_kernel(
    const int* __restrict__ rowptr, const int2* __restrict__ csr,
    const float* __restrict__ dinv, const float* __restrict__ b3,
    const int* __restrict__ batch, const __half* __restrict__ yin,
    float* __restrict__ sums, float* __restrict__ cnt, int n) {
    __shared__ float bsh[NF];
    __shared__ float xr[BN][NF];
    __shared__ int gs[BN];
    if (threadIdx.x < NF) bsh[threadIdx.x] = b3[threadIdx.x];
    __syncthreads();
    int t = threadIdx.x;
    int nd = t / NF, f = t - nd * NF;
    int base = blockIdx.x * BN;
    int nvalid = n - base; if (nvalid > BN) nvalid = BN;
    int d = base + nd;
    bool act = (nd < BN) && (d < n);
    if (act) {
        int start = (d == 0) ? 0 : rowptr[d - 1], end = rowptr[d];
        float g = gather_seg(csr, yin, start, end, f);
        float h = dinv[d] * (g + __half2float(yin[(size_t)d * HSTR + f])) + bsh[f];
        xr[nd][f] = fmaxf(h, 0.f);
        if (f == 0) gs[nd] = batch[d];
    }
    __syncthreads();
    if (nvalid <= 0) return;
    if (t < NF) {           // per-feature: run-length pooled atomics (batch sorted)
        float run = 0.f;
        int gcur = gs[0];
        for (int k = 0; k < nvalid; ++k) {
            int g = gs[k];
            if (g != gcur) { ATOMIC_ADD_F32(&sums[gcur * NF + t], run); run = 0.f; gcur = g; }
            run += xr[k][t];
        }
        ATOMIC_ADD_F32(&sums[gcur * NF + t], run);
    } else if (t == NF) {   // node counts per graph
        float run = 0.f;
        int gcur = gs[0];
        for (int k = 0; k < nvalid; ++k) {
            int g = gs[k];
            if (g != gcur) { ATOMIC_ADD_F32(&cnt[gcur], run); run = 0.f; gcur = g; }
            run += 1.f;
        }
        ATOMIC_ADD_F32(&cnt[gcur], run);
    }
}

// --- MLP + softmax: one block per graph; fp32 output -------------------------
__global__ __launch_bounds__(256) void mlp_kernel(
    const float* __restrict__ sums, const float* __restrict__ cnt,
    const float* __restrict__ Wp,  const float* __restrict__ bp,
    const float* __restrict__ Wf1, const float* __restrict__ bf1,
    const float* __restrict__ Wf2, const float* __restrict__ bf2,
    const float* __restrict__ Wo,  const float* __restrict__ bo,
    float* __restrict__ out) {
    int g = blockIdx.x;
    int t = threadIdx.x;
    __shared__ float xr[NF], h1[128], h2[256], h3[64];
    if (t < NF) xr[t] = sums[g * NF + t] / fmaxf(cnt[g], 1.0f);
    __syncthreads();
    if (t < 128) {
        float v = bp[t];
        #pragma unroll
        for (int f = 0; f < NF; ++f) v += xr[f] * Wp[f * 128 + t];
        h1[t] = v >= 0.f ? v : 0.01f * v;
    }
    __syncthreads();
    {
        float v = bf1[t];
        for (int k = 0; k < 128; ++k) v += h1[k] * Wf1[k * 256 + t];
        h2[t] = v >= 0.f ? v : 0.01f * v;
    }
    __syncthreads();
    if (t < 64) {
        float v = bf2[t];
        for (int k = 0; k < 256; ++k) v += h2[k] * Wf2[k * 64 + t];
        h3[t] = v >= 0.f ? v : 0.01f * v;
    }
    __syncthreads();
    if (t == 0) {
        float lg[5];
        float m = -1e30f;
        for (int j = 0; j < 5; ++j) {
            float v = bo[j];
            for (int k = 0; k < 64; ++k) v += h3[k] * Wo[k * 5 + j];
            lg[j] = v;
            m = fmaxf(m, v);
        }
        float den = 0.f;
        for (int j = 0; j < 5; ++j) { lg[j] = __expf(lg[j] - m); den += lg[j]; }
        for (int j = 0; j < 5; ++j) out[g * 5 + j] = lg[j] / den;
    }
}

extern "C" void kernel_launch(void* const* d_in, const int* in_sizes, int n_in,
                              void* d_out, int out_size, void* d_ws, size_t ws_size,
                              hipStream_t stream) {
    const float* x     = (const float*)d_in[0];
    const int*   ei    = (const int*)d_in[1];
    const float* ew    = (const float*)d_in[2];
    const int*   batch = (const int*)d_in[3];
    const float* W1 = (const float*)d_in[4];
    const float* b1 = (const float*)d_in[5];
    const float* W2 = (const float*)d_in[6];
    const float* b2 = (const float*)d_in[7];
    const float* W3 = (const float*)d_in[8];
    const float* b3 = (const float*)d_in[9];
    const float* Wp  = (const float*)d_in[10];
    const float* bp  = (const float*)d_in[11];
    const float* Wf1 = (const float*)d_in[12];
    const float* bf1 = (const float*)d_in[13];
    const float* Wf2 = (const float*)d_in[14];
    const float* bf2 = (const float*)d_in[15];
    const float* Wo  = (const float*)d_in[16];
    const float* bo  = (const float*)d_in[17];

    const int n = in_sizes[0] / NF;   // 100000
    const int E = in_sizes[2];        // 3200000
    const int B = out_size / 5;       // 64

    // ws layout (4B words): csr int2[E] | rowptr[n] | dinv[n] | yA half[n*HSTR/2 words] | yB | sums[B*NF] | cnt[B]
    const size_t y_words = ((size_t)n * HSTR) / 2;
    const size_t need_words = (size_t)2 * E + 2 * (size_t)n + 2 * y_words + (size_t)B * NF + B;
    if (ws_size < need_words * 4) {
        sentinel_kernel<<<(out_size + 63) / 64, 64, 0, stream>>>((float*)d_out, out_size);
        return;
    }

    int2*  csr    = (int2*)d_ws;
    int*   rowptr = (int*)d_ws + (size_t)2 * E;
    float* dinv   = (float*)((int*)d_ws + (size_t)2 * E + n);
    __half* yA    = (__half*)(dinv + n);
    __half* yB    = yA + (size_t)n * HSTR;
    float* sums   = (float*)(yB + (size_t)n * HSTR);
    float* cnt    = sums + (size_t)B * NF;

    hipMemsetAsync(rowptr, 0, (size_t)n * sizeof(int), stream);
    hipMemsetAsync(sums, 0, (size_t)(B * NF + B) * sizeof(float), stream);

    int nb_e = (E + 255) / 256;
    int nb_n = (n + 255) / 256;
    int nb_g = (n + BN - 1) / BN;

    hist_kernel<<<nb_e, 256, 0, stream>>>(ei, rowptr, E);
    scan_kernel<<<1, SCAN_T, 0, stream>>>(rowptr, n);
    scatter_kernel<<<nb_e, 256, 0, stream>>>(ei, ew, rowptr, csr, E);

    node_l1_kernel<<<nb_n, 256, 0, stream>>>(x, rowptr, csr, W1, dinv, yA, n);
    layer_kernel<<<nb_g, 256, 0, stream>>>(rowptr, csr, dinv, b1, W2, yA, yB, n);
    layer_kernel<<<nb_g, 256, 0, stream>>>(rowptr, csr, dinv, b2, W3, yB, yA, n);
    final_pool_kernel<<<nb_g, 256, 0, stream>>>(rowptr, csr, dinv, b3, batch, yA,
                                                sums, cnt, n);
    mlp_kernel<<<B, 256, 0, stream>>>(sums, cnt, Wp, bp, Wf1, bf1, Wf2, bf2, Wo, bo,
                                      (float*)d_out);
}

// Round 10
// 481.633 us; speedup vs baseline: 2.5793x; 1.9204x over previous
//
#include <hip/hip_runtime.h>
#include <hip/hip_fp16.h>

#define NF 21
#define HSTR 32       // fp16 row stride (halves): 64B rows -> 1 cache line per row
#define BN 12         // nodes per block in gather kernels (12*21 = 252 lanes used)
#define SCAN_T 1024
#define BSH 7         // bucket shift: 128 nodes per bucket
#define BSZ 128       // nodes per bucket
#define NBMAX 1024    // max buckets supported (n <= 131072)
#define BINR 49       // rounds per bin block
#define BINCHUNK (BINR * 256)

#define ATOMIC_ADD_F32(p, v) unsafeAtomicAdd((p), (v))

// Diagnostic: fills output with a recognizable sentinel if ws_size is insufficient.
__global__ __launch_bounds__(64) void sentinel_kernel(float* out, int m) {
    int i = blockIdx.x * 64 + threadIdx.x;
    if (i < m) out[i] = 0.109375f;
}

// --- Bucketed CSR build ------------------------------------------------------
// Pass A: per-bucket edge counts, LDS-aggregated (200K global atomics, not 3.2M)
__global__ __launch_bounds__(256) void bucket_count_kernel(
    const int* __restrict__ ei, int* __restrict__ bases, int E, int nb) {
    __shared__ int lc[NBMAX];
    for (int i = threadIdx.x; i < nb; i += 256) lc[i] = 0;
    __syncthreads();
    int base = blockIdx.x * BINCHUNK;
    for (int r = 0; r < BINR; ++r) {
        int e = base + r * 256 + threadIdx.x;
        if (e < E) atomicAdd(&lc[ei[E + e] >> BSH], 1);
    }
    __syncthreads();
    for (int i = threadIdx.x; i < nb; i += 256)
        if (lc[i]) atomicAdd(&bases[i], lc[i]);
}

// Pass B: single-block exclusive scan in-place; also copies result to cur[]
__global__ __launch_bounds__(SCAN_T) void scan_copy_kernel(
    int* __restrict__ data, int* __restrict__ cur, int n) {
    __shared__ int sd[SCAN_T];
    int t = threadIdx.x;
    int chunk = (n + SCAN_T - 1) / SCAN_T;
    int base = t * chunk;
    int s = 0;
    for (int i = 0; i < chunk; ++i) { int idx = base + i; if (idx < n) s += data[idx]; }
    sd[t] = s;
    __syncthreads();
    for (int off = 1; off < SCAN_T; off <<= 1) {
        int v = (t >= off) ? sd[t - off] : 0;
        __syncthreads();
        sd[t] += v;
        __syncthreads();
    }
    int run = sd[t] - s;
    for (int i = 0; i < chunk; ++i) {
        int idx = base + i;
        if (idx < n) { int v = data[idx]; data[idx] = run; cur[idx] = run; run += v; }
    }
}

// Pass C: bin edges into bucket-contiguous storage. Block-aggregated bump:
// LDS atomic for local offset, one global atomic per (block,bucket) for base.
__global__ __launch_bounds__(256) void bin_kernel(
    const int* __restrict__ ei, const float* __restrict__ ew,
    int* __restrict__ cur, unsigned int* __restrict__ binned,
    __half* __restrict__ bw, int E, int nb) {
    __shared__ int lcnt[NBMAX];
    __shared__ int lbase[NBMAX];
    for (int i = threadIdx.x; i < nb; i += 256) lcnt[i] = 0;
    __syncthreads();
    int base = blockIdx.x * BINCHUNK;
    int pl[BINR];
    #pragma unroll
    for (int r = 0; r < BINR; ++r) {
        int e = base + r * 256 + threadIdx.x;
        pl[r] = (e < E) ? atomicAdd(&lcnt[ei[E + e] >> BSH], 1) : 0;
    }
    __syncthreads();
    for (int i = threadIdx.x; i < nb; i += 256)
        if (lcnt[i]) lbase[i] = atomicAdd(&cur[i], lcnt[i]);
    __syncthreads();
    #pragma unroll
    for (int r = 0; r < BINR; ++r) {
        int e = base + r * 256 + threadIdx.x;
        if (e < E) {
            int d = ei[E + e];
            int b = d >> BSH;
            int pos = lbase[b] + pl[r];
            binned[pos] = (unsigned int)ei[e] | ((unsigned int)(d & (BSZ - 1)) << 17);
            bw[pos] = __float2half(ew[e]);
        }
    }
}

// Pass D: one block per bucket — LDS hist + scan over 128 local dsts, write
// rowptr (segment ends) and final CSR entries into an L2-resident window.
__global__ __launch_bounds__(256) void build_kernel(
    const int* __restrict__ bases, const int* __restrict__ cur,
    const unsigned int* __restrict__ binned, const __half* __restrict__ bw,
    int* __restrict__ rowptr, int2* __restrict__ csr, int n) {
    __shared__ int h[BSZ], s[BSZ], bump[BSZ];
    int b = blockIdx.x;
    int t = threadIdx.x;
    int base = bases[b], end = cur[b];
    int cntb = end - base;
    if (t < BSZ) { h[t] = 0; bump[t] = 0; }
    __syncthreads();
    for (int i = t; i < cntb; i += 256)
        atomicAdd(&h[binned[base + i] >> 17], 1);
    __syncthreads();
    if (t < BSZ) s[t] = h[t];
    __syncthreads();
    for (int off = 1; off < BSZ; off <<= 1) {
        int v = 0;
        if (t < BSZ && t >= off) v = s[t - off];
        __syncthreads();
        if (t < BSZ) s[t] += v;
        __syncthreads();
    }
    // s = inclusive prefix; rowptr[d] = segment end (existing convention)
    if (t < BSZ) {
        int d = b * BSZ + t;
        if (d < n) rowptr[d] = base + s[t];
    }
    __syncthreads();
    for (int i = t; i < cntb; i += 256) {
        unsigned int v = binned[base + i];
        int dl = v >> 17;
        int src = v & 0x1FFFF;
        int p = atomicAdd(&bump[dl], 1);
        int pos = base + (s[dl] - h[dl]) + p;
        csr[pos] = make_int2(src, __float_as_int(__half2float(bw[base + i])));
    }
}

// --- Layer 1: deg from CSR, dinv, y = dinv*(x@W1) (fp16 out) ----------------
__global__ __launch_bounds__(256) void node_l1_kernel(
    const float* __restrict__ x, const int* __restrict__ rowptr,
    const int2* __restrict__ csr, const float* __restrict__ W,
    float* __restrict__ dinv, __half* __restrict__ y, int n) {
    __shared__ float Ws[NF * NF];
    for (int i = threadIdx.x; i < NF * NF; i += 256) Ws[i] = W[i];
    __syncthreads();
    int i = blockIdx.x * 256 + threadIdx.x;
    if (i >= n) return;
    int start = (i == 0) ? 0 : rowptr[i - 1], end = rowptr[i];
    float deg = 0.f;
    int e = start;
    for (; e + 3 < end; e += 4) {
        int2 c0 = csr[e], c1 = csr[e + 1], c2 = csr[e + 2], c3 = csr[e + 3];
        deg += __int_as_float(c0.y) + __int_as_float(c1.y)
             + __int_as_float(c2.y) + __int_as_float(c3.y);
    }
    for (; e < end; ++e) deg += __int_as_float(csr[e].y);
    float di = rsqrtf(deg + 1.0f);
    dinv[i] = di;
    float xr[NF];
    #pragma unroll
    for (int f = 0; f < NF; ++f) xr[f] = x[i * NF + f];
    #pragma unroll
    for (int j = 0; j < NF; ++j) {
        float v = 0.f;
        #pragma unroll
        for (int f = 0; f < NF; ++f) v += xr[f] * Ws[f * NF + j];
        y[(size_t)i * HSTR + j] = __float2half(di * v);
    }
}

// gather over one node's CSR segment, unrolled x8 for memory-level parallelism
static __device__ __forceinline__ float gather_seg(
    const int2* __restrict__ csr, const __half* __restrict__ yin,
    int start, int end, int f) {
    float g = 0.f;
    int e = start;
    for (; e + 7 < end; e += 8) {
        int2 c0 = csr[e + 0], c1 = csr[e + 1], c2 = csr[e + 2], c3 = csr[e + 3];
        int2 c4 = csr[e + 4], c5 = csr[e + 5], c6 = csr[e + 6], c7 = csr[e + 7];
        float a0 = __half2float(yin[(size_t)c0.x * HSTR + f]);
        float a1 = __half2float(yin[(size_t)c1.x * HSTR + f]);
        float a2 = __half2float(yin[(size_t)c2.x * HSTR + f]);
        float a3 = __half2float(yin[(size_t)c3.x * HSTR + f]);
        float a4 = __half2float(yin[(size_t)c4.x * HSTR + f]);
        float a5 = __half2float(yin[(size_t)c5.x * HSTR + f]);
        float a6 = __half2float(yin[(size_t)c6.x * HSTR + f]);
        float a7 = __half2float(yin[(size_t)c7.x * HSTR + f]);
        g += __int_as_float(c0.y) * a0 + __int_as_float(c1.y) * a1
           + __int_as_float(c2.y) * a2 + __int_as_float(c3.y) * a3
           + __int_as_float(c4.y) * a4 + __int_as_float(c5.y) * a5
           + __int_as_float(c6.y) * a6 + __int_as_float(c7.y) * a7;
    }
    for (; e < end; ++e) {
        int2 c = csr[e];
        g += __int_as_float(c.y) * __half2float(yin[(size_t)c.x * HSTR + f]);
    }
    return g;
}

// --- Fused GCN layer (layers 2,3): gather + prev finish + matvec ------------
__global__ __launch_bounds__(256) void layer_kernel(
    const int* __restrict__ rowptr, const int2* __restrict__ csr,
    const float* __restrict__ dinv, const float* __restrict__ bprev,
    const float* __restrict__ W,
    const __half* __restrict__ yin, __half* __restrict__ yout, int n) {
    __shared__ float Ws[NF * NF];
    __shared__ float bsh[NF];
    __shared__ float xr[BN][NF];
    for (int i = threadIdx.x; i < NF * NF; i += 256) Ws[i] = W[i];
    if (threadIdx.x < NF) bsh[threadIdx.x] = bprev[threadIdx.x];
    __syncthreads();
    int t = threadIdx.x;
    int nd = t / NF, f = t - nd * NF;
    int d = blockIdx.x * BN + nd;
    bool act = (nd < BN) && (d < n);
    float di = 0.f;
    if (act) {
        di = dinv[d];
        int start = (d == 0) ? 0 : rowptr[d - 1], end = rowptr[d];
        float g = gather_seg(csr, yin, start, end, f);
        xr[nd][f] = di * (g + __half2float(yin[(size_t)d * HSTR + f])) + bsh[f];
    }
    __syncthreads();
    if (act) {
        float v = 0.f;
        #pragma unroll
        for (int k = 0; k < NF; ++k) v += xr[nd][k] * Ws[k * NF + f];
        yout[(size_t)d * HSTR + f] = __float2half(di * v);
    }
}

// --- Final fused: gather + relu + block-level mean-pool partials ------------
__global__ __launch_bounds__(256) void final_pool_kernel(
    const int* __restrict__ rowptr, const int2* __restrict__ csr,
    const float* __restrict__ dinv, const float* __restrict__ b3,
    const int* __restrict__ batch, const __half* __restrict__ yin,
    float* __restrict__ sums, float* __restrict__ cnt, int n) {
    __shared__ float bsh[NF];
    __shared__ float xr[BN][NF];
    __shared__ int gs[BN];
    if (threadIdx.x < NF) bsh[threadIdx.x] = b3[threadIdx.x];
    __syncthreads();
    int t = threadIdx.x;
    int nd = t / NF, f = t - nd * NF;
    int base = blockIdx.x * BN;
    int nvalid = n - base; if (nvalid > BN) nvalid = BN;
    int d = base + nd;
    bool act = (nd < BN) && (d < n);
    if (act) {
        int start = (d == 0) ? 0 : rowptr[d - 1], end = rowptr[d];
        float g = gather_seg(csr, yin, start, end, f);
        float h = dinv[d] * (g + __half2float(yin[(size_t)d * HSTR + f])) + bsh[f];
        xr[nd][f] = fmaxf(h, 0.f);
        if (f == 0) gs[nd] = batch[d];
    }
    __syncthreads();
    if (nvalid <= 0) return;
    if (t < NF) {
        float run = 0.f;
        int gcur = gs[0];
        for (int k = 0; k < nvalid; ++k) {
            int g = gs[k];
            if (g != gcur) { ATOMIC_ADD_F32(&sums[gcur * NF + t], run); run = 0.f; gcur = g; }
            run += xr[k][t];
        }
        ATOMIC_ADD_F32(&sums[gcur * NF + t], run);
    } else if (t == NF) {
        float run = 0.f;
        int gcur = gs[0];
        for (int k = 0; k < nvalid; ++k) {
            int g = gs[k];
            if (g != gcur) { ATOMIC_ADD_F32(&cnt[gcur], run); run = 0.f; gcur = g; }
            run += 1.f;
        }
        ATOMIC_ADD_F32(&cnt[gcur], run);
    }
}

// --- MLP + softmax: one block per graph; fp32 output -------------------------
__global__ __launch_bounds__(256) void mlp_kernel(
    const float* __restrict__ sums, const float* __restrict__ cnt,
    const float* __restrict__ Wp,  const float* __restrict__ bp,
    const float* __restrict__ Wf1, const float* __restrict__ bf1,
    const float* __restrict__ Wf2, const float* __restrict__ bf2,
    const float* __restrict__ Wo,  const float* __restrict__ bo,
    float* __restrict__ out) {
    int g = blockIdx.x;
    int t = threadIdx.x;
    __shared__ float xr[NF], h1[128], h2[256], h3[64];
    if (t < NF) xr[t] = sums[g * NF + t] / fmaxf(cnt[g], 1.0f);
    __syncthreads();
    if (t < 128) {
        float v = bp[t];
        #pragma unroll
        for (int f = 0; f < NF; ++f) v += xr[f] * Wp[f * 128 + t];
        h1[t] = v >= 0.f ? v : 0.01f * v;
    }
    __syncthreads();
    {
        float v = bf1[t];
        for (int k = 0; k < 128; ++k) v += h1[k] * Wf1[k * 256 + t];
        h2[t] = v >= 0.f ? v : 0.01f * v;
    }
    __syncthreads();
    if (t < 64) {
        float v = bf2[t];
        for (int k = 0; k < 256; ++k) v += h2[k] * Wf2[k * 64 + t];
        h3[t] = v >= 0.f ? v : 0.01f * v;
    }
    __syncthreads();
    if (t == 0) {
        float lg[5];
        float m = -1e30f;
        for (int j = 0; j < 5; ++j) {
            float v = bo[j];
            for (int k = 0; k < 64; ++k) v += h3[k] * Wo[k * 5 + j];
            lg[j] = v;
            m = fmaxf(m, v);
        }
        float den = 0.f;
        for (int j = 0; j < 5; ++j) { lg[j] = __expf(lg[j] - m); den += lg[j]; }
        for (int j = 0; j < 5; ++j) out[g * 5 + j] = lg[j] / den;
    }
}

extern "C" void kernel_launch(void* const* d_in, const int* in_sizes, int n_in,
                              void* d_out, int out_size, void* d_ws, size_t ws_size,
                              hipStream_t stream) {
    const float* x     = (const float*)d_in[0];
    const int*   ei    = (const int*)d_in[1];
    const float* ew    = (const float*)d_in[2];
    const int*   batch = (const int*)d_in[3];
    const float* W1 = (const float*)d_in[4];
    const float* b1 = (const float*)d_in[5];
    const float* W2 = (const float*)d_in[6];
    const float* b2 = (const float*)d_in[7];
    const float* W3 = (const float*)d_in[8];
    const float* b3 = (const float*)d_in[9];
    const float* Wp  = (const float*)d_in[10];
    const float* bp  = (const float*)d_in[11];
    const float* Wf1 = (const float*)d_in[12];
    const float* bf1 = (const float*)d_in[13];
    const float* Wf2 = (const float*)d_in[14];
    const float* bf2 = (const float*)d_in[15];
    const float* Wo  = (const float*)d_in[16];
    const float* bo  = (const float*)d_in[17];

    const int n = in_sizes[0] / NF;   // 100000
    const int E = in_sizes[2];        // 3200000
    const int B = out_size / 5;       // 64
    const int nb = (n + BSZ - 1) >> BSH;  // 782 buckets

    // ws layout (4B words):
    //   csr int2[E] | rowptr[n] | dinv[n] | yregion max(n*HSTR, E) words
    //   | sums[B*NF] | cnt[B] | bw half[E] | bases[NBMAX] | cur[NBMAX]
    const size_t y_words = (size_t)n * HSTR > (size_t)E ? (size_t)n * HSTR : (size_t)E;
    const size_t need_words = (size_t)2 * E + 2 * (size_t)n + y_words
                            + (size_t)B * NF + B + ((size_t)E + 1) / 2 + 2 * NBMAX;
    if (ws_size < need_words * 4 || nb > NBMAX) {
        sentinel_kernel<<<(out_size + 63) / 64, 64, 0, stream>>>((float*)d_out, out_size);
        return;
    }

    int*   wsw    = (int*)d_ws;
    int2*  csr    = (int2*)wsw;
    int*   rowptr = wsw + (size_t)2 * E;
    float* dinv   = (float*)(wsw + (size_t)2 * E + n);
    int*   yreg   = wsw + (size_t)2 * E + 2 * (size_t)n;
    __half* yA    = (__half*)yreg;
    __half* yB    = yA + (size_t)n * HSTR;
    unsigned int* binned = (unsigned int*)yreg;            // overlay (dead before yA/yB live)
    float* sums   = (float*)(yreg + y_words);
    float* cnt    = sums + (size_t)B * NF;
    __half* bw    = (__half*)(cnt + B);
    int*   bases  = (int*)(bw + 2 * (((size_t)E + 1) / 2));
    int*   cur    = bases + NBMAX;

    hipMemsetAsync(bases, 0, (size_t)nb * sizeof(int), stream);
    hipMemsetAsync(sums, 0, (size_t)(B * NF + B) * sizeof(float), stream);

    int nb_bin = (E + BINCHUNK - 1) / BINCHUNK;   // 256 blocks
    int nb_n   = (n + 255) / 256;
    int nb_g   = (n + BN - 1) / BN;

    bucket_count_kernel<<<nb_bin, 256, 0, stream>>>(ei, bases, E, nb);
    scan_copy_kernel<<<1, SCAN_T, 0, stream>>>(bases, cur, nb);
    bin_kernel<<<nb_bin, 256, 0, stream>>>(ei, ew, cur, binned, bw, E, nb);
    build_kernel<<<nb, 256, 0, stream>>>(bases, cur, binned, bw, rowptr, csr, n);

    node_l1_kernel<<<nb_n, 256, 0, stream>>>(x, rowptr, csr, W1, dinv, yA, n);
    layer_kernel<<<nb_g, 256, 0, stream>>>(rowptr, csr, dinv, b1, W2, yA, yB, n);
    layer_kernel<<<nb_g, 256, 0, stream>>>(rowptr, csr, dinv, b2, W3, yB, yA, n);
    final_pool_kernel<<<nb_g, 256, 0, stream>>>(rowptr, csr, dinv, b3, batch, yA,
                                                sums, cnt, n);
    mlp_kernel<<<B, 256, 0, stream>>>(sums, cnt, Wp, bp, Wf1, bf1, Wf2, bf2, Wo, bo,
                                      (float*)d_out);
}